// Round 1
// baseline (212.162 us; speedup 1.0000x reference)
//
#include <hip/hip_runtime.h>
#include <hip/hip_bf16.h>

#define B_  32
#define N_  128
#define AH_ 512
#define AW_ 512

// ---------------------------------------------------------------------------
// Zero the per-image accumulators (d_ws is poisoned once and never re-poisoned,
// so we must clear it ourselves every launch; tiny kernel is graph-capture safe).
// ---------------------------------------------------------------------------
__global__ void zero_sums_kernel(float* sums) {
    int t = threadIdx.x;
    if (t < B_) sums[t] = 0.0f;
}

// ---------------------------------------------------------------------------
// One block per (image b, row y). 256 threads.
// Phase 1: threads 0..127 evaluate box params; boxes covering this row are
//          compacted (order-preserving) into LDS.
// Phase 2: all 256 threads sweep the 512-pixel row; per pixel, reverse scan
//          of the compacted list with early break = "last valid box wins".
// Block sum -> atomicAdd into per-image sum.
// ---------------------------------------------------------------------------
__global__ __launch_bounds__(256) void row_bce_kernel(
    const float* __restrict__ att,
    const float* __restrict__ bboxs,
    const int*   __restrict__ img_h_p,
    const int*   __restrict__ img_w_p,
    float*       __restrict__ img_sums)
{
    const int blk = blockIdx.x;        // b*AH_ + y
    const int b   = blk >> 9;          // / 512
    const int y   = blk & (AH_ - 1);
    const int t   = threadIdx.x;
    const int lane = t & 63;
    const int wid  = t >> 6;

    __shared__ int   s_x1[N_];
    __shared__ int   s_x2[N_];
    __shared__ float s_x1m[N_];
    __shared__ float s_x2m[N_];
    __shared__ float s_row[N_];
    __shared__ int   s_cnt[2];
    __shared__ float s_wsum[4];

    const float fw = (float)(*img_w_p);
    const float fh = (float)(*img_h_p);
    const float sxs = (float)AW_ / fw;
    const float sys = (float)AH_ / fh;

    // ---- Phase 1: per-box row coverage ----
    bool  active = false;
    int   cx1 = 0, cx2 = 0;
    float cx1m = 0.0f, cx2m = 0.0f, rowval = 0.0f;

    if (t < N_) {
        const float* bp = bboxs + ((size_t)b * N_ + t) * 5;
        const float c0 = bp[0], c1 = bp[1], c2 = bp[2], c3 = bp[3], lab = bp[4];
        const bool valid = (lab != -1.0f) && (c0 <= fw) && (c1 <= fh)
                                          && (c2 <= fw) && (c3 <= fh);
        if (valid) {
            const float bx1 = c0 * sxs, by1 = c1 * sys;
            const float bx2 = c2 * sxs, by2 = c3 * sys;
            const float fx1 = floorf(bx1), fy1 = floorf(by1);
            const float x1m = fx1 + 1.0f - bx1;
            const float y1m = fy1 + 1.0f - by1;
            const float x2m = bx2 - floorf(bx2);
            const float y2m = by2 - floorf(by2);
            const int x1 = (int)fmaxf(fx1, 0.0f);
            const int y1 = (int)fmaxf(fy1, 0.0f);
            const int x2 = (int)fminf(ceilf(bx2) + 1.0f, (float)AW_);
            const int y2 = (int)fminf(ceilf(by2) + 1.0f, (float)AH_);
            if (y >= y1 && y < y2) {
                active = true;
                cx1 = x1; cx2 = x2; cx1m = x1m; cx2m = x2m;
                rowval = ((y == y1)     ? y1m : 1.0f)
                       * ((y == y2 - 1) ? y2m : 1.0f);
            }
        }
    }

    // Order-preserving compaction: wave0 owns boxes 0..63, wave1 owns 64..127.
    const unsigned long long bal = __ballot(active);
    if (wid < 2 && lane == 0) s_cnt[wid] = __popcll(bal);
    __syncthreads();
    const int cnt0 = s_cnt[0];
    const int cnt  = cnt0 + s_cnt[1];
    if (active) {
        int slot = __popcll(bal & ((1ull << lane) - 1ull)) + (wid == 1 ? cnt0 : 0);
        s_x1[slot]  = cx1;
        s_x2[slot]  = cx2;
        s_x1m[slot] = cx1m;
        s_x2m[slot] = cx2m;
        s_row[slot] = rowval;
    }
    __syncthreads();

    // ---- Phase 2: pixel sweep ----
    const float* prow = att + ((size_t)b * AH_ + y) * AW_;
    float acc = 0.0f;
    #pragma unroll
    for (int xo = 0; xo < AW_; xo += 256) {
        const int x = xo + t;
        const float p   = prow[x];
        const float lp  = fmaxf(logf(p),    -100.0f);
        const float l1  = fmaxf(log1pf(-p), -100.0f);
        float val = 0.0f;
        for (int i = cnt - 1; i >= 0; --i) {
            if (x >= s_x1[i] && x < s_x2[i]) {
                val = s_row[i]
                    * ((x == s_x1[i])     ? s_x1m[i] : 1.0f)
                    * ((x == s_x2[i] - 1) ? s_x2m[i] : 1.0f);
                break;
            }
        }
        acc += l1 + val * (lp - l1);
    }

    // ---- Block reduction ----
    #pragma unroll
    for (int off = 32; off; off >>= 1) acc += __shfl_down(acc, off, 64);
    if (lane == 0) s_wsum[wid] = acc;
    __syncthreads();
    if (t == 0) {
        atomicAdd(&img_sums[b], s_wsum[0] + s_wsum[1] + s_wsum[2] + s_wsum[3]);
    }
}

// ---------------------------------------------------------------------------
// Finalize: per-image any_valid gate, negate+normalize, batch mean.
// ---------------------------------------------------------------------------
__global__ void final_kernel(
    const float* __restrict__ bboxs,
    const int*   __restrict__ img_h_p,
    const int*   __restrict__ img_w_p,
    const float* __restrict__ img_sums,
    float*       __restrict__ out)
{
    const int t = threadIdx.x;   // 64 threads
    float loss = 0.0f;
    if (t < B_) {
        const float fw = (float)(*img_w_p);
        const float fh = (float)(*img_h_p);
        bool anyv = false;
        const float* bp = bboxs + (size_t)t * N_ * 5;
        for (int n = 0; n < N_; ++n) {
            const float c0 = bp[n * 5 + 0];
            const float c1 = bp[n * 5 + 1];
            const float c2 = bp[n * 5 + 2];
            const float c3 = bp[n * 5 + 3];
            const float lab = bp[n * 5 + 4];
            anyv |= (lab != -1.0f) && (c0 <= fw) && (c1 <= fh)
                                   && (c2 <= fw) && (c3 <= fh);
        }
        loss = anyv ? (-img_sums[t] * (1.0f / (float)(AH_ * AW_))) : 0.0f;
    }
    #pragma unroll
    for (int off = 32; off; off >>= 1) loss += __shfl_down(loss, off, 64);
    if (t == 0) out[0] = loss * (1.0f / (float)B_);
}

extern "C" void kernel_launch(void* const* d_in, const int* in_sizes, int n_in,
                              void* d_out, int out_size, void* d_ws, size_t ws_size,
                              hipStream_t stream)
{
    const float* att   = (const float*)d_in[0];   // (32,1,512,512) f32
    const float* bboxs = (const float*)d_in[1];   // (32,128,5) f32
    const int*   img_h = (const int*)d_in[2];     // scalar
    const int*   img_w = (const int*)d_in[3];     // scalar
    float* out = (float*)d_out;
    float* img_sums = (float*)d_ws;               // 32 floats

    zero_sums_kernel<<<1, 64, 0, stream>>>(img_sums);
    row_bce_kernel<<<B_ * AH_, 256, 0, stream>>>(att, bboxs, img_h, img_w, img_sums);
    final_kernel<<<1, 64, 0, stream>>>(bboxs, img_h, img_w, img_sums, out);
}

// Round 2
// 60.624 us; speedup vs baseline: 3.4996x; 3.4996x over previous
//
#include <hip/hip_runtime.h>
#include <hip/hip_bf16.h>

#define B_  32
#define N_  128
#define AH_ 512
#define AW_ 512

// ---------------------------------------------------------------------------
// One block per (image b, row y). 256 threads.
// Phase 1: threads 0..127 evaluate box params; boxes covering this row are
//          compacted (order-preserving) into LDS (packed: int2 + float4).
// Phase 2: all 256 threads sweep the 512-pixel row; per pixel, FORWARD scan
//          with overwrite = "last valid box wins" (branchless, no early-out).
// Block sum -> ws[blockIdx.x] (NO atomics -- previous version serialized
// 16384 atomicAdds on one cacheline, ~180us).
// ---------------------------------------------------------------------------
__global__ __launch_bounds__(256) void row_bce_kernel(
    const float* __restrict__ att,
    const float* __restrict__ bboxs,
    const int*   __restrict__ img_h_p,
    const int*   __restrict__ img_w_p,
    float*       __restrict__ row_sums)
{
    const int blk = blockIdx.x;        // b*AH_ + y
    const int b   = blk >> 9;          // / 512
    const int y   = blk & (AH_ - 1);
    const int t   = threadIdx.x;
    const int lane = t & 63;
    const int wid  = t >> 6;

    __shared__ int2   s_xr[N_];   // {x1, x2}
    __shared__ float4 s_f[N_];    // {row, row*x1m, x2m, unused}
    __shared__ int    s_cnt[2];
    __shared__ float  s_wsum[4];

    const float fw = (float)(*img_w_p);
    const float fh = (float)(*img_h_p);
    const float sxs = (float)AW_ / fw;
    const float sys = (float)AH_ / fh;

    // ---- Phase 1: per-box row coverage ----
    bool  active = false;
    int   cx1 = 0, cx2 = 0;
    float cx1m = 0.0f, cx2m = 0.0f, rowval = 0.0f;

    if (t < N_) {
        const float* bp = bboxs + ((size_t)b * N_ + t) * 5;
        const float c0 = bp[0], c1 = bp[1], c2 = bp[2], c3 = bp[3], lab = bp[4];
        const bool valid = (lab != -1.0f) && (c0 <= fw) && (c1 <= fh)
                                          && (c2 <= fw) && (c3 <= fh);
        if (valid) {
            const float bx1 = c0 * sxs, by1 = c1 * sys;
            const float bx2 = c2 * sxs, by2 = c3 * sys;
            const float fx1 = floorf(bx1), fy1 = floorf(by1);
            const float x1m = fx1 + 1.0f - bx1;
            const float y1m = fy1 + 1.0f - by1;
            const float x2m = bx2 - floorf(bx2);
            const float y2m = by2 - floorf(by2);
            const int x1 = (int)fmaxf(fx1, 0.0f);
            const int y1 = (int)fmaxf(fy1, 0.0f);
            const int x2 = (int)fminf(ceilf(bx2) + 1.0f, (float)AW_);
            const int y2 = (int)fminf(ceilf(by2) + 1.0f, (float)AH_);
            if (y >= y1 && y < y2) {
                active = true;
                cx1 = x1; cx2 = x2; cx1m = x1m; cx2m = x2m;
                rowval = ((y == y1)     ? y1m : 1.0f)
                       * ((y == y2 - 1) ? y2m : 1.0f);
            }
        }
    }

    // Order-preserving compaction: wave0 owns boxes 0..63, wave1 owns 64..127.
    const unsigned long long bal = __ballot(active);
    if (wid < 2 && lane == 0) s_cnt[wid] = __popcll(bal);
    __syncthreads();
    const int cnt0 = s_cnt[0];
    const int cnt  = cnt0 + s_cnt[1];
    if (active) {
        int slot = __popcll(bal & ((1ull << lane) - 1ull)) + (wid == 1 ? cnt0 : 0);
        s_xr[slot] = make_int2(cx1, cx2);
        s_f[slot]  = make_float4(rowval, rowval * cx1m, cx2m, 0.0f);
    }
    __syncthreads();

    // ---- Phase 2: pixel sweep (forward overwrite = last-wins, branchless) ----
    const float* prow = att + ((size_t)b * AH_ + y) * AW_;
    float acc = 0.0f;
    #pragma unroll
    for (int xo = 0; xo < AW_; xo += 256) {
        const int x = xo + t;
        const float p  = prow[x];
        const float lp = fmaxf(__logf(p),        -100.0f);
        const float l1 = fmaxf(__logf(1.0f - p), -100.0f);
        float val = 0.0f;
        for (int i = 0; i < cnt; ++i) {
            const int2   xr = s_xr[i];
            const float4 f  = s_f[i];
            if (x >= xr.x && x < xr.y) {
                val = ((x == xr.x)     ? f.y : f.x)
                    * ((x == xr.y - 1) ? f.z : 1.0f);
            }
        }
        acc += l1 + val * (lp - l1);
    }

    // ---- Block reduction -> per-row partial (no atomics) ----
    #pragma unroll
    for (int off = 32; off; off >>= 1) acc += __shfl_down(acc, off, 64);
    if (lane == 0) s_wsum[wid] = acc;
    __syncthreads();
    if (t == 0) {
        row_sums[blk] = s_wsum[0] + s_wsum[1] + s_wsum[2] + s_wsum[3];
    }
}

// ---------------------------------------------------------------------------
// Finalize: segmented reduce of 512 row partials per image, any_valid gate,
// negate+normalize, batch mean. One block, 1024 threads (32 per image).
// ---------------------------------------------------------------------------
__global__ __launch_bounds__(1024) void final_kernel(
    const float* __restrict__ bboxs,
    const int*   __restrict__ img_h_p,
    const int*   __restrict__ img_w_p,
    const float* __restrict__ row_sums,
    float*       __restrict__ out)
{
    const int t = threadIdx.x;
    const int b = t >> 5;        // image 0..31
    const int j = t & 31;        // worker within image

    __shared__ float s_sum[1024];
    __shared__ int   s_any[1024];
    __shared__ float s_loss[B_];

    // per-image row-partial reduction
    float s = 0.0f;
    for (int r = j; r < AH_; r += 32) s += row_sums[b * AH_ + r];
    s_sum[t] = s;

    // any_valid: each worker checks 4 boxes
    const float fw = (float)(*img_w_p);
    const float fh = (float)(*img_h_p);
    int av = 0;
    const float* bp = bboxs + (size_t)b * N_ * 5;
    for (int n = j * 4; n < j * 4 + 4; ++n) {
        const float c0 = bp[n * 5 + 0];
        const float c1 = bp[n * 5 + 1];
        const float c2 = bp[n * 5 + 2];
        const float c3 = bp[n * 5 + 3];
        const float lab = bp[n * 5 + 4];
        av |= ((lab != -1.0f) && (c0 <= fw) && (c1 <= fh)
                              && (c2 <= fw) && (c3 <= fh)) ? 1 : 0;
    }
    s_any[t] = av;
    __syncthreads();

    if (j == 0) {
        float sum = 0.0f;
        int anyv = 0;
        for (int k = 0; k < 32; ++k) {
            sum  += s_sum[b * 32 + k];
            anyv |= s_any[b * 32 + k];
        }
        s_loss[b] = anyv ? (-sum * (1.0f / (float)(AH_ * AW_))) : 0.0f;
    }
    __syncthreads();

    if (t == 0) {
        float total = 0.0f;
        for (int k = 0; k < B_; ++k) total += s_loss[k];
        out[0] = total * (1.0f / (float)B_);
    }
}

extern "C" void kernel_launch(void* const* d_in, const int* in_sizes, int n_in,
                              void* d_out, int out_size, void* d_ws, size_t ws_size,
                              hipStream_t stream)
{
    const float* att   = (const float*)d_in[0];   // (32,1,512,512) f32
    const float* bboxs = (const float*)d_in[1];   // (32,128,5) f32
    const int*   img_h = (const int*)d_in[2];     // scalar
    const int*   img_w = (const int*)d_in[3];     // scalar
    float* out = (float*)d_out;
    float* row_sums = (float*)d_ws;               // B_*AH_ = 16384 floats (64 KB)

    row_bce_kernel<<<B_ * AH_, 256, 0, stream>>>(att, bboxs, img_h, img_w, row_sums);
    final_kernel<<<1, 1024, 0, stream>>>(bboxs, img_h, img_w, row_sums, out);
}

// Round 3
// 29.445 us; speedup vs baseline: 7.2055x; 2.0589x over previous
//
#include <hip/hip_runtime.h>
#include <hip/hip_bf16.h>

#define B_  32
#define N_  128
#define AH_ 512
#define AW_ 512

// ---------------------------------------------------------------------------
// Row rasterize + BCE. 128 threads = 2 waves; each wave owns ONE row with its
// own LDS slice (no cross-wave coupling except the two cheap barriers).
//
// Per wave:
//  Phase 1: lanes evaluate boxes {lane, lane+64}; row-covering boxes are
//           order-preserving compacted into LDS (ballot/popc prefix).
//  Phase 2: sequential loop over cnt (~14) boxes; each box SPAN-WRITES its
//           row value into s_mask[x1..x2) (predicated lane-contiguous
//           ds_write, ~ceil(width/64) instrs) then lanes 0/1 overwrite the
//           two fractional edge pixels. DS ops of a wave retire in order ->
//           last-box-wins preserved with NO barrier in the loop.
//  Phase 3: float4 BCE sweep over the 512 pixels, wave reduce, store partial.
//
// (R2 scanned all boxes per pixel: 512*14 iters/row; this does ~14*2 span
// writes/row -> ~3x fewer VALU instrs.)
// ---------------------------------------------------------------------------
__global__ __launch_bounds__(128) void row_bce_kernel(
    const float* __restrict__ att,
    const float* __restrict__ bboxs,
    const int*   __restrict__ img_h_p,
    const int*   __restrict__ img_w_p,
    float*       __restrict__ row_sums)
{
    const int t    = threadIdx.x;
    const int lane = t & 63;
    const int wid  = t >> 6;                 // 0..1 -> which row of the pair
    const int b    = blockIdx.x >> 8;        // 8192 blocks = 32 images * 256 pairs
    const int y    = ((blockIdx.x & 255) << 1) | wid;

    __shared__ int2   s_xr[2][N_];           // {x1, x2}
    __shared__ float4 s_f[2][N_];            // {row, row*x1m, row*x2m, x2m}
    __shared__ float  s_mask[2][AW_];

    const float fw  = (float)(*img_w_p);
    const float fh  = (float)(*img_h_p);
    const float sxs = (float)AW_ / fw;
    const float sys = (float)AH_ / fh;

    // ---- mask init: 2x float4 stores per lane covers the 512-px row ----
    float4* mrow4 = (float4*)s_mask[wid];
    const float4 z = make_float4(0.f, 0.f, 0.f, 0.f);
    mrow4[lane]      = z;
    mrow4[lane + 64] = z;

    // ---- Phase 1: evaluate boxes lane and lane+64 ----
    bool  act[2];
    int2  xr[2];
    float4 f[2];
    #pragma unroll
    for (int k = 0; k < 2; ++k) {
        const int n = lane + 64 * k;
        act[k] = false;
        const float* bp = bboxs + ((size_t)b * N_ + n) * 5;
        const float c0 = bp[0], c1 = bp[1], c2 = bp[2], c3 = bp[3], lab = bp[4];
        const bool valid = (lab != -1.0f) && (c0 <= fw) && (c1 <= fh)
                                          && (c2 <= fw) && (c3 <= fh);
        if (valid) {
            const float bx1 = c0 * sxs, by1 = c1 * sys;
            const float bx2 = c2 * sxs, by2 = c3 * sys;
            const float fx1 = floorf(bx1), fy1 = floorf(by1);
            const float x1m = fx1 + 1.0f - bx1;
            const float y1m = fy1 + 1.0f - by1;
            const float x2m = bx2 - floorf(bx2);
            const float y2m = by2 - floorf(by2);
            const int x1 = (int)fmaxf(fx1, 0.0f);
            const int y1 = (int)fmaxf(fy1, 0.0f);
            const int x2 = (int)fminf(ceilf(bx2) + 1.0f, (float)AW_);
            const int y2 = (int)fminf(ceilf(by2) + 1.0f, (float)AH_);
            if (y >= y1 && y < y2) {
                act[k] = true;
                const float row = ((y == y1)     ? y1m : 1.0f)
                                * ((y == y2 - 1) ? y2m : 1.0f);
                xr[k] = make_int2(x1, x2);
                f[k]  = make_float4(row, row * x1m, row * x2m, x2m);
            }
        }
    }

    // ---- order-preserving compaction (per wave) ----
    const unsigned long long bal0 = __ballot(act[0]);
    const unsigned long long bal1 = __ballot(act[1]);
    const unsigned long long ltm  = (1ull << lane) - 1ull;
    const int c0n = __popcll(bal0);
    const int cnt = c0n + __popcll(bal1);
    if (act[0]) {
        const int slot = __popcll(bal0 & ltm);
        s_xr[wid][slot] = xr[0];
        s_f[wid][slot]  = f[0];
    }
    if (act[1]) {
        const int slot = c0n + __popcll(bal1 & ltm);
        s_xr[wid][slot] = xr[1];
        s_f[wid][slot]  = f[1];
    }
    __syncthreads();

    // ---- Phase 2: sequential span rasterize (last-wins) ----
    float* mrow = s_mask[wid];
    for (int i = 0; i < cnt; ++i) {
        const int2   e = s_xr[wid][i];
        const float4 g = s_f[wid][i];
        for (int x = e.x + lane; x < e.y; x += 64) mrow[x] = g.x;
        // fractional edges (span writes retire first: same-wave DS order)
        if (lane == 0 && e.x < e.y) mrow[e.x] = (e.x == e.y - 1) ? g.y * g.w : g.y;
        if (lane == 1 && e.y - 1 > e.x) mrow[e.y - 1] = g.z;
    }
    __syncthreads();

    // ---- Phase 3: BCE sweep (float4) ----
    const float4* p4 = (const float4*)(att + ((size_t)b * AH_ + y) * AW_);
    float acc = 0.0f;
    #pragma unroll
    for (int h = 0; h < 2; ++h) {
        const float4 p = p4[lane + 64 * h];
        const float4 m = mrow4[lane + 64 * h];
        const float pv[4] = {p.x, p.y, p.z, p.w};
        const float mv[4] = {m.x, m.y, m.z, m.w};
        #pragma unroll
        for (int j = 0; j < 4; ++j) {
            const float lp = fmaxf(__logf(pv[j]),        -100.0f);
            const float l1 = fmaxf(__logf(1.0f - pv[j]), -100.0f);
            acc += l1 + mv[j] * (lp - l1);
        }
    }

    #pragma unroll
    for (int off = 32; off; off >>= 1) acc += __shfl_down(acc, off, 64);
    if (lane == 0) row_sums[b * AH_ + y] = acc;
}

// ---------------------------------------------------------------------------
// Per-image reduce: 32 blocks x 256 threads. Sum 512 row partials, compute
// any_valid over 128 boxes, write per-image loss to img_loss (deterministic,
// no atomics).
// ---------------------------------------------------------------------------
__global__ __launch_bounds__(256) void image_reduce_kernel(
    const float* __restrict__ bboxs,
    const int*   __restrict__ img_h_p,
    const int*   __restrict__ img_w_p,
    const float* __restrict__ row_sums,
    float*       __restrict__ img_loss)
{
    const int b    = blockIdx.x;
    const int t    = threadIdx.x;
    const int lane = t & 63;
    const int wid  = t >> 6;

    float s = row_sums[b * AH_ + t] + row_sums[b * AH_ + 256 + t];

    bool av = false;
    if (t < N_) {
        const float fw = (float)(*img_w_p);
        const float fh = (float)(*img_h_p);
        const float* bp = bboxs + ((size_t)b * N_ + t) * 5;
        av = (bp[4] != -1.0f) && (bp[0] <= fw) && (bp[1] <= fh)
                              && (bp[2] <= fw) && (bp[3] <= fh);
    }

    #pragma unroll
    for (int off = 32; off; off >>= 1) s += __shfl_down(s, off, 64);
    const unsigned long long anym = __ballot(av);

    __shared__ float s_w[4];
    __shared__ int   s_a[4];
    if (lane == 0) { s_w[wid] = s; s_a[wid] = (anym != 0ull); }
    __syncthreads();
    if (t == 0) {
        const float sum = s_w[0] + s_w[1] + s_w[2] + s_w[3];
        const int   anyv = s_a[0] | s_a[1] | s_a[2] | s_a[3];
        img_loss[b] = anyv ? (-sum * (1.0f / (float)(AH_ * AW_))) : 0.0f;
    }
}

// ---------------------------------------------------------------------------
// Batch mean over 32 per-image losses.
// ---------------------------------------------------------------------------
__global__ void combine_kernel(const float* __restrict__ img_loss,
                               float* __restrict__ out)
{
    const int t = threadIdx.x;   // 64
    float v = (t < B_) ? img_loss[t] : 0.0f;
    #pragma unroll
    for (int off = 32; off; off >>= 1) v += __shfl_down(v, off, 64);
    if (t == 0) out[0] = v * (1.0f / (float)B_);
}

extern "C" void kernel_launch(void* const* d_in, const int* in_sizes, int n_in,
                              void* d_out, int out_size, void* d_ws, size_t ws_size,
                              hipStream_t stream)
{
    const float* att   = (const float*)d_in[0];   // (32,1,512,512) f32
    const float* bboxs = (const float*)d_in[1];   // (32,128,5) f32
    const int*   img_h = (const int*)d_in[2];     // scalar
    const int*   img_w = (const int*)d_in[3];     // scalar
    float* out = (float*)d_out;

    float* row_sums = (float*)d_ws;               // 16384 floats
    float* img_loss = row_sums + B_ * AH_;        // 32 floats

    row_bce_kernel<<<B_ * AH_ / 2, 128, 0, stream>>>(att, bboxs, img_h, img_w, row_sums);
    image_reduce_kernel<<<B_, 256, 0, stream>>>(bboxs, img_h, img_w, row_sums, img_loss);
    combine_kernel<<<1, 64, 0, stream>>>(img_loss, out);
}